// Round 12
// baseline (121.756 us; speedup 1.0000x reference)
//
#include <hip/hip_runtime.h>
#include <hip/hip_bf16.h>

// Grouped GEMM: out[e,s,o] = sum_i x[e,s,i] * w[e,o,i]
// E=8, S=8192 tok/expert, O=512, I=1024, fp32 in/out, bf16 MFMA compute.
// R12: residency fix. R11's loop verbatim, but 4-wave blocks (256 thr),
//      BM=128 x BN=256, grid 1024 -> TWO blocks co-resident per CU
//      (252 regs/wave = 2 waves/SIMD; one 8-wave block monopolized the CU
//      and serialized MFMA/LDS/fabric pools on every barrier). Independent
//      block barriers let pools overlap (m114 implicit wave-level overlap).

#define NE 8
#define NO 512
#define NI 1024
#define NS 8192

#define BM 128
#define BN 256
#define BK 32
#define NT (NI / BK)   // 32 K-tiles
#define LDA 40         // padded A row stride in shorts (32 data + 8 pad)

typedef __attribute__((ext_vector_type(4))) float f32x4;
typedef __attribute__((ext_vector_type(4))) short s16x4;
typedef __attribute__((ext_vector_type(8))) short s16x8;

__device__ __forceinline__ s16x4 cvt4(f32x4 a) {
    s16x4 r;
    r[0] = (short)__builtin_bit_cast(unsigned short, __float2bfloat16(a[0]));
    r[1] = (short)__builtin_bit_cast(unsigned short, __float2bfloat16(a[1]));
    r[2] = (short)__builtin_bit_cast(unsigned short, __float2bfloat16(a[2]));
    r[3] = (short)__builtin_bit_cast(unsigned short, __float2bfloat16(a[3]));
    return r;
}

// ---- pass 0: W fp32 -> bf16, MFMA B-fragment lane order (R3-verified) ----
// Wpk(e, g, kt32, l, j) = bf16(W[e][g*16 + (l&15)][kt32*32 + (l>>4)*8 + j])
__global__ __launch_bounds__(256)
void pack_w(const float* __restrict__ W, short* __restrict__ Wpk) {
    int idx  = blockIdx.x * 256 + threadIdx.x;  // 0 .. 524287
    int l    = idx & 63;
    int kt32 = (idx >> 6) & 31;
    int g    = (idx >> 11) & 31;
    int e    = idx >> 16;
    const float* src = W + (size_t)(e * NO + g * 16 + (l & 15)) * NI
                         + kt32 * 32 + (l >> 4) * 8;
    f32x4 a = *(const f32x4*)src;
    f32x4 b = *(const f32x4*)(src + 4);
    s16x4 lo = cvt4(a), hi = cvt4(b);
    s16x8 r;
    r[0] = lo[0]; r[1] = lo[1]; r[2] = lo[2]; r[3] = lo[3];
    r[4] = hi[0]; r[5] = hi[1]; r[6] = hi[2]; r[7] = hi[3];
    *(s16x8*)(Wpk + (size_t)idx * 8) = r;
}

// ---- main grouped GEMM ----
__global__ __launch_bounds__(256, 2)
void moe_gemm(const float* __restrict__ X,
              const short* __restrict__ Wpk,
              float* __restrict__ Out) {
    // 1024 blocks = 8 experts x 64 mblk x 2 nblk. e = bid&7: consecutive
    // blocks round-robin XCDs -> each XCD runs one expert (Wpk_e L2-resident);
    // nblk siblings (8 bids apart, same XCD) share the A tile via L2.
    int bid  = blockIdx.x;
    int e    = bid & 7;
    int nblk = (bid >> 3) & 1;
    int mblk = bid >> 4;

    const float* Ap = X   + ((size_t)e * NS + (size_t)mblk * BM) * NI;
    const short* Bp = Wpk + (size_t)e * (32 * 32 * 64 * 8);
    float*       Cp = Out + ((size_t)e * NS + (size_t)mblk * BM) * NO + nblk * BN;

    __shared__ short lA[2][BM * LDA];   // 2 x 10 KiB

    const int tid  = threadIdx.x;
    const int lane = tid & 63;
    const int wn   = tid >> 6;    // 0..3 -> cols [wn*64, +64) within BN=256
    const int l15  = lane & 15;
    const int lhi  = lane >> 4;   // 0..3
    const int gbase = nblk * 16 + wn * 4;   // global 16-col fragment group

    f32x4 acc[8][4];
#pragma unroll
    for (int i = 0; i < 8; ++i)
#pragma unroll
        for (int j = 0; j < 4; ++j)
            acc[i][j] = (f32x4){0.f, 0.f, 0.f, 0.f};

    f32x4 ar[4];                 // A staging: 4 x f32x4 / thread
    s16x8 bfA[4], bfB[4], af[8]; // named B double-buffer (rule #20)

    // A: unit u = tid + i*256 over 1024 f32x4-chunks of the 128x32 tile.
#define AISSUE(kt)                                                             \
    do {                                                                       \
        _Pragma("unroll") for (int i = 0; i < 4; ++i) {                        \
            int u = tid + i * 256;                                             \
            ar[i] = *(const f32x4*)(Ap + (size_t)(u >> 3) * NI +               \
                                    (kt) * BK + (u & 7) * 4);                  \
        }                                                                      \
    } while (0)

#define AWRITE(buf)                                                            \
    do {                                                                       \
        _Pragma("unroll") for (int i = 0; i < 4; ++i) {                        \
            int u = tid + i * 256;                                             \
            *(s16x4*)&lA[buf][(u >> 3) * LDA + (u & 7) * 4] = cvt4(ar[i]);     \
        }                                                                      \
    } while (0)

    // B frag (gbase+ni, kt): 16 B/lane, consecutive lanes contiguous (L2).
#define BLOAD(kt, dst)                                                         \
    do {                                                                       \
        _Pragma("unroll") for (int ni = 0; ni < 4; ++ni)                       \
            dst[ni] = *(const s16x8*)(Bp +                                     \
                ((size_t)((gbase + ni) * 32 + (kt)) * 64 + lane) * 8);         \
    } while (0)

    // A frags: row mi*16+l15, k-chunk lhi (16 B). Pad spreads banks evenly.
#define READA(c)                                                               \
    do {                                                                       \
        _Pragma("unroll") for (int mi = 0; mi < 8; ++mi)                       \
            af[mi] = *(const s16x8*)&lA[c][(mi * 16 + l15) * LDA + lhi * 8];   \
    } while (0)

#define MFMA(bf)                                                               \
    do {                                                                       \
        __builtin_amdgcn_s_setprio(1);                                         \
        _Pragma("unroll") for (int mi = 0; mi < 8; ++mi)                       \
            _Pragma("unroll") for (int ni = 0; ni < 4; ++ni)                   \
                acc[mi][ni] = __builtin_amdgcn_mfma_f32_16x16x32_bf16(         \
                    af[mi], bf[ni], acc[mi][ni], 0, 0, 0);                     \
        __builtin_amdgcn_s_setprio(0);                                         \
    } while (0)

#define BAR()   __builtin_amdgcn_s_barrier()
#define LGKM0() asm volatile("s_waitcnt lgkmcnt(0)" ::: "memory")
#define VM(n)   asm volatile("s_waitcnt vmcnt(" #n ")" ::: "memory")

    // ---- Prologue. Invariant entering tile kt: lA[kt&1]=A(kt) staged,
    //      bf_cur=B(kt) ready, outstanding = [A4(kt+1), B4(kt+1)]. ----
    AISSUE(0);
    VM(0);
    AWRITE(0);
    BLOAD(0, bfA);     // B4(0)
    AISSUE(1);         // A4(1)
    BLOAD(1, bfB);     // B4(1)
    VM(8);             // drain B4(0); keep A4(1)+B4(1)
    LGKM0();
    BAR();

    // Steady state: queue entering tile = [B4(kt), A4(kt+1), B4(kt+1)] = 12;
    // VM(4) drains B4(kt)+A4(kt+1), keeps newest B4. Never 0 mid-loop.
#define TILE_MAIN(kt, bfc)                                                     \
    do {                                                                       \
        VM(4);                                                                 \
        AWRITE(((kt) + 1) & 1);                                                \
        AISSUE((kt) + 2);                                                      \
        READA((kt) & 1);                                                       \
        MFMA(bfc);                                                             \
        BLOAD((kt) + 2, bfc);       /* reuse just-consumed buffer */           \
        LGKM0();                                                               \
        BAR();                                                                 \
    } while (0)

#pragma unroll 1
    for (int kt2 = 0; kt2 < NT / 2 - 1; ++kt2) {
        const int kt = kt2 * 2;
        TILE_MAIN(kt, bfA);
        TILE_MAIN(kt + 1, bfB);
    }
    // Tail: kt = 30, 31. Entering queue = [B4(30), A4(31), B4(31)].
    {
        VM(4);                      // drain B4(30)+A4(31); keep B4(31)
        AWRITE(1);
        READA(0);
        MFMA(bfA);
        LGKM0();
        BAR();
        VM(0);                      // drain B4(31)
        READA(1);
        MFMA(bfB);
    }

    // Epilogue: D frag (mi,ni): m = lhi*4 + rr, n = l15 (verified layout).
#pragma unroll
    for (int mi = 0; mi < 8; ++mi) {
#pragma unroll
        for (int rr = 0; rr < 4; ++rr) {
            int row   = mi * 16 + lhi * 4 + rr;
            float* cp = Cp + (size_t)row * NO + wn * 64 + l15;
#pragma unroll
            for (int ni = 0; ni < 4; ++ni)
                cp[ni * 16] = acc[mi][ni][rr];
        }
    }
#undef AISSUE
#undef AWRITE
#undef BLOAD
#undef READA
#undef MFMA
#undef TILE_MAIN
#undef BAR
#undef LGKM0
#undef VM
}

extern "C" void kernel_launch(void* const* d_in, const int* in_sizes, int n_in,
                              void* d_out, int out_size, void* d_ws, size_t ws_size,
                              hipStream_t stream) {
    const float* X = (const float*)d_in[0];
    const float* W = (const float*)d_in[1];
    float* Out     = (float*)d_out;
    short* Wpk     = (short*)d_ws;   // 8 MiB

    hipLaunchKernelGGL(pack_w, dim3(2048), dim3(256), 0, stream, W, Wpk);
    hipLaunchKernelGGL(moe_gemm, dim3(NE * (NS / BM) * (NO / BN)), dim3(256), 0,
                       stream, X, Wpk, Out);
}

// Round 13
// 114.106 us; speedup vs baseline: 1.0670x; 1.0670x over previous
//
#include <hip/hip_runtime.h>
#include <hip/hip_bf16.h>

// Grouped GEMM: out[e,s,o] = sum_i x[e,s,i] * w[e,o,i]
// E=8, S=8192 tok/expert, O=512, I=1024, fp32 in/out, bf16 MFMA compute.
// R13: consume-first BK=64 periods on R11's frame (BM=128 x BN=512, 8 waves,
//      reg-B from fragment-packed Wpk, expert-per-XCD).
//      Period j (tiles 2j,2j+1):
//        VM(4)  drain B8(j) [issued ~8000cy ago, free]; keep A4(j+1)
//        READA kk0 -> 32 MFMA -> BLOAD(2j+2) -> READA kk1 -> 32 MFMA -> BLOAD(2j+3)
//        VM(8)  drain A4(j+1); keep B8(j+1)
//        AWRITE -> AISSUE(j+2) -> LGKM0 -> BAR
//      A-LDS: 128x64 bf16 rows (128 B), XOR phys=c16^(row&7) write+read
//      (R8/R9-measured 0 bank conflicts). vmcnt never 0 mid-loop.

#define NE 8
#define NO 512
#define NI 1024
#define NS 8192

#define BM 128
#define BK 64
#define NP (NI / BK)   // 16 periods (32 BK32 B-tiles)

typedef __attribute__((ext_vector_type(4))) float f32x4;
typedef __attribute__((ext_vector_type(4))) short s16x4;
typedef __attribute__((ext_vector_type(8))) short s16x8;

__device__ __forceinline__ s16x4 cvt4(f32x4 a) {
    s16x4 r;
    r[0] = (short)__builtin_bit_cast(unsigned short, __float2bfloat16(a[0]));
    r[1] = (short)__builtin_bit_cast(unsigned short, __float2bfloat16(a[1]));
    r[2] = (short)__builtin_bit_cast(unsigned short, __float2bfloat16(a[2]));
    r[3] = (short)__builtin_bit_cast(unsigned short, __float2bfloat16(a[3]));
    return r;
}

// ---- pass 0: W fp32 -> bf16, MFMA B-fragment lane order (R3-verified) ----
// Wpk(e, g, kt32, l, j) = bf16(W[e][g*16 + (l&15)][kt32*32 + (l>>4)*8 + j])
__global__ __launch_bounds__(256)
void pack_w(const float* __restrict__ W, short* __restrict__ Wpk) {
    int idx  = blockIdx.x * 256 + threadIdx.x;  // 0 .. 524287
    int l    = idx & 63;
    int kt32 = (idx >> 6) & 31;
    int g    = (idx >> 11) & 31;
    int e    = idx >> 16;
    const float* src = W + (size_t)(e * NO + g * 16 + (l & 15)) * NI
                         + kt32 * 32 + (l >> 4) * 8;
    f32x4 a = *(const f32x4*)src;
    f32x4 b = *(const f32x4*)(src + 4);
    s16x4 lo = cvt4(a), hi = cvt4(b);
    s16x8 r;
    r[0] = lo[0]; r[1] = lo[1]; r[2] = lo[2]; r[3] = lo[3];
    r[4] = hi[0]; r[5] = hi[1]; r[6] = hi[2]; r[7] = hi[3];
    *(s16x8*)(Wpk + (size_t)idx * 8) = r;
}

// ---- main grouped GEMM ----
__global__ __launch_bounds__(512, 1)
void moe_gemm(const float* __restrict__ X,
              const short* __restrict__ Wpk,
              float* __restrict__ Out) {
    // 512 blocks = 8 experts x 64 mblk. e = bid&7 -> one expert per XCD.
    int bid  = blockIdx.x;
    int e    = bid & 7;
    int mblk = bid >> 3;

    const float* Ap = X   + ((size_t)e * NS + (size_t)mblk * BM) * NI;
    const short* Bp = Wpk + (size_t)e * (32 * 32 * 64 * 8);
    float*       Cp = Out + ((size_t)e * NS + (size_t)mblk * BM) * NO;

    __shared__ short lA[2][BM * BK];   // 2 x 16 KiB

    const int tid  = threadIdx.x;
    const int lane = tid & 63;
    const int wn   = tid >> 6;    // 0..7 -> cols [wn*64, +64)
    const int l15  = lane & 15;
    const int lhi  = lane >> 4;   // 0..3

    f32x4 acc[8][4];
#pragma unroll
    for (int i = 0; i < 8; ++i)
#pragma unroll
        for (int j = 0; j < 4; ++j)
            acc[i][j] = (f32x4){0.f, 0.f, 0.f, 0.f};

    f32x4 ar[4];                 // A staging: 4 x f32x4 / thread (128x64 fp32)
    s16x8 bfA[4], bfB[4], af[8]; // named B double-buffer (rule #20)

    // A: unit u = tid + i*512 over 2048 f32x4-chunks of the 128x64 tile.
    // row = u>>4 (0..127), c4 = u&15. 16 lanes x 16B = 256 B/row, coalesced.
#define AISSUE(p)                                                              \
    do {                                                                       \
        _Pragma("unroll") for (int i = 0; i < 4; ++i) {                        \
            int u = tid + i * 512;                                             \
            ar[i] = *(const f32x4*)(Ap + (size_t)(u >> 4) * NI +               \
                                    (p) * BK + (u & 15) * 4);                  \
        }                                                                      \
    } while (0)

    // A write: 16B-chunk c16 = c4>>1, phys = c16 ^ (row&7). (R8-verified)
#define AWRITE(buf)                                                            \
    do {                                                                       \
        _Pragma("unroll") for (int i = 0; i < 4; ++i) {                        \
            int u    = tid + i * 512;                                          \
            int row  = u >> 4;                                                 \
            int c4   = u & 15;                                                 \
            int phys = (c4 >> 1) ^ (row & 7);                                  \
            *(s16x4*)&lA[buf][row * BK + phys * 8 + (c4 & 1) * 4] = cvt4(ar[i]); \
        }                                                                      \
    } while (0)

    // B frag (wn*4+ni, kt32): 16 B/lane, lanes contiguous (L2). kt32 = 0..31.
#define BLOAD(kt, dst)                                                         \
    do {                                                                       \
        _Pragma("unroll") for (int ni = 0; ni < 4; ++ni)                       \
            dst[ni] = *(const s16x8*)(Bp +                                     \
                ((size_t)((wn * 4 + ni) * 32 + (kt)) * 64 + lane) * 8);        \
    } while (0)

    // A frags, k-half kk: row r = mi*16+l15, phys = (kk*4+lhi) ^ (r&7). (R9-verified)
#define READA(c, kk)                                                           \
    do {                                                                       \
        _Pragma("unroll") for (int mi = 0; mi < 8; ++mi) {                     \
            int r  = mi * 16 + l15;                                            \
            af[mi] = *(const s16x8*)&lA[c][r * BK +                            \
                                           ((((kk) * 4 + lhi) ^ (r & 7)) << 3)]; \
        }                                                                      \
    } while (0)

#define MFMA(bf)                                                               \
    do {                                                                       \
        __builtin_amdgcn_s_setprio(1);                                         \
        _Pragma("unroll") for (int mi = 0; mi < 8; ++mi)                       \
            _Pragma("unroll") for (int ni = 0; ni < 4; ++ni)                   \
                acc[mi][ni] = __builtin_amdgcn_mfma_f32_16x16x32_bf16(         \
                    af[mi], bf[ni], acc[mi][ni], 0, 0, 0);                     \
        __builtin_amdgcn_s_setprio(0);                                         \
    } while (0)

#define BAR()   __builtin_amdgcn_s_barrier()
#define LGKM0() asm volatile("s_waitcnt lgkmcnt(0)" ::: "memory")
#define VM(n)   asm volatile("s_waitcnt vmcnt(" #n ")" ::: "memory")

    // ---- Prologue. Invariant entering period j:
    //      lA[j&1] = A(j); bfA,bfB = B(2j),B(2j+1) pending in queue;
    //      vm queue = [B8(j) oldest, A4(j+1)] = 12. ----
    AISSUE(0);
    VM(0);
    AWRITE(0);
    BLOAD(0, bfA);     // B8(0)...
    BLOAD(1, bfB);
    AISSUE(1);         // A4(1)
    LGKM0();
    BAR();

#pragma unroll 1
    for (int j = 0; j < NP - 1; ++j) {
        const int c = j & 1;
        // consume-first: everything below VM(4) is resident.
        VM(4);                       // drain B8(j); keep A4(j+1)
        READA(c, 0);
        MFMA(bfA);
        BLOAD(2 * j + 2, bfA);       // B for period j+1, first half
        READA(c, 1);
        MFMA(bfB);
        BLOAD(2 * j + 3, bfB);       // B for period j+1, second half
        // stage-behind:
        VM(8);                       // drain A4(j+1); keep B8(j+1)
        AWRITE(c ^ 1);
        if (j < NP - 2) AISSUE(j + 2);
        LGKM0();                     // own ds_writes visible
        BAR();
    }
    // ---- Period 15: consume only. Queue entering: [B8(15)] = 8. ----
    VM(4);
    READA(1, 0);
    MFMA(bfA);
    VM(0);
    READA(1, 1);
    MFMA(bfB);

    // Epilogue: D frag (mi,ni): m = lhi*4 + rr, n = l15 (verified layout).
#pragma unroll
    for (int mi = 0; mi < 8; ++mi) {
#pragma unroll
        for (int rr = 0; rr < 4; ++rr) {
            int row   = mi * 16 + lhi * 4 + rr;
            float* cp = Cp + (size_t)row * NO + wn * 64 + l15;
#pragma unroll
            for (int ni = 0; ni < 4; ++ni)
                cp[ni * 16] = acc[mi][ni][rr];
        }
    }
#undef AISSUE
#undef AWRITE
#undef BLOAD
#undef READA
#undef MFMA
#undef BAR
#undef LGKM0
#undef VM
}

extern "C" void kernel_launch(void* const* d_in, const int* in_sizes, int n_in,
                              void* d_out, int out_size, void* d_ws, size_t ws_size,
                              hipStream_t stream) {
    const float* X = (const float*)d_in[0];
    const float* W = (const float*)d_in[1];
    float* Out     = (float*)d_out;
    short* Wpk     = (short*)d_ws;   // 8 MiB

    hipLaunchKernelGGL(pack_w, dim3(2048), dim3(256), 0, stream, W, Wpk);
    hipLaunchKernelGGL(moe_gemm, dim3(NE * (NS / BM)), dim3(512), 0,
                       stream, X, Wpk, Out);
}